// Round 1
// 100.067 us; speedup vs baseline: 1.0013x; 1.0013x over previous
//
#include <hip/hip_runtime.h>
#include <hip/hip_bf16.h>

#define IN_DIM 128

typedef int   int4v   __attribute__((ext_vector_type(4)));
typedef float float4v __attribute__((ext_vector_type(4)));

// Kernel 1: per-node projection, quad-split layout. UNCHANGED (absmax sits at
// the 2^-7 threshold; accumulation order must be preserved bit-for-bit).
// pa[n] = (dot(x[n], W[0,0:128]), dot(x[n], W[1,0:128]))   -- used by src side
// pd[n] = (dot(x[n], W[0,128:256]), dot(x[n], W[1,128:256])) -- used by dst side
//
// Lane l -> node (l>>2), dim-slice (l&3)*32..+32. Each lane keeps 4 partial
// dots over its 32-dim slice; reduction is a 2-stage intra-quad butterfly
// (all 4 lanes end with full sums; lane sub==0 writes pa, sub==1 writes pd).
// W (512 floats) staged once per block into padded LDS (table stride 144,
// sub stride 36 -> conflict-free ds_read_b128 with 16-lane broadcast).
__global__ __launch_bounds__(256) void node_proj_kernel(
    const float* __restrict__ x,   // [N, 128]
    const float* __restrict__ W,   // [2, 256]
    float2* __restrict__ pa,       // [N] (a0,a1)
    float2* __restrict__ pd,       // [N] (d0,d1)
    int n_nodes) {
    __shared__ __align__(16) float wlds[4 * 144];  // [4 tables][4 subs][36]

    for (int i = threadIdx.x; i < 512; i += 256) {
        int c    = i >> 8;
        int d    = i & 255;
        int half = d >> 7;
        int k    = d & 127;
        int sub  = k >> 5;
        int kk   = k & 31;
        wlds[(half * 2 + c) * 144 + sub * 36 + kk] = W[i];
    }
    __syncthreads();

    const int lane = threadIdx.x & 63;
    const int sub  = lane & 3;        // which 32-dim slice
    const int nl   = lane >> 2;       // node within wave (0..15)
    const int wave = threadIdx.x >> 6;
    const int node = (blockIdx.x * 4 + wave) * 16 + nl;

    if (node < n_nodes) {
        const float* xb = x + (size_t)node * IN_DIM + sub * 32;
        const float* wt = wlds + sub * 36;

        float a0 = 0.f, a1 = 0.f, d0 = 0.f, d1 = 0.f;
        #pragma unroll
        for (int j = 0; j < 8; ++j) {
            const float4 xv = *(const float4*)(xb + j * 4);
            const float4 w0 = *(const float4*)(wt + 0 * 144 + j * 4);
            const float4 w1 = *(const float4*)(wt + 1 * 144 + j * 4);
            const float4 w2 = *(const float4*)(wt + 2 * 144 + j * 4);
            const float4 w3 = *(const float4*)(wt + 3 * 144 + j * 4);
            a0 += xv.x * w0.x + xv.y * w0.y + xv.z * w0.z + xv.w * w0.w;
            a1 += xv.x * w1.x + xv.y * w1.y + xv.z * w1.z + xv.w * w1.w;
            d0 += xv.x * w2.x + xv.y * w2.y + xv.z * w2.z + xv.w * w2.w;
            d1 += xv.x * w3.x + xv.y * w3.y + xv.z * w3.z + xv.w * w3.w;
        }

        // 2-stage intra-quad butterfly: afterwards ALL quad lanes hold sums.
        a0 += __shfl_xor(a0, 1, 64);
        a1 += __shfl_xor(a1, 1, 64);
        d0 += __shfl_xor(d0, 1, 64);
        d1 += __shfl_xor(d1, 1, 64);
        a0 += __shfl_xor(a0, 2, 64);
        a1 += __shfl_xor(a1, 2, 64);
        d0 += __shfl_xor(d0, 2, 64);
        d1 += __shfl_xor(d1, 2, 64);

        if (sub == 0) pa[node] = make_float2(a0, a1);
        if (sub == 1) pd[node] = make_float2(d0, d1);
    }
}

// Kernel 2: per-edge scoring from two 0.8 MB float2 tables (L2-resident).
// score[e][c] = pa[src[e]].c + pd[dst[e]].c + b[c]
//
// 4 edges per thread: one int4 load per index row (16 B, coalesced), 8x 8B
// gathers, two float4 stores. Streaming traffic (idx in, out store) uses
// nontemporal hints so the 10 MB of stream data does NOT evict the 1.6 MB
// pa/pd tables from L2 -- the 1.25M random gathers stay L2-hot.
__global__ __launch_bounds__(256) void edge_score_kernel(
    const int* __restrict__ idx,     // [2, E] (src row then dst row), int32
    const float2* __restrict__ pa,   // [N]
    const float2* __restrict__ pd,   // [N]
    const float* __restrict__ b,     // [2]
    float4v* __restrict__ out,       // [E/2] (2 edges x 2 classes each)
    int n_edges) {
    const int t = blockIdx.x * blockDim.x + threadIdx.x;
    const int e = t * 4;
    if (e >= n_edges) return;

    const float b0 = b[0];
    const float b1 = b[1];

    // Fast path requires n_edges % 4 == 0 so the dst-row int4 load is
    // 16B-aligned (true for the bench: 625000). Otherwise scalar fallback.
    if (((n_edges & 3) == 0) & (e + 3 < n_edges)) {
        const int4v s = __builtin_nontemporal_load((const int4v*)(idx + e));
        const int4v d = __builtin_nontemporal_load((const int4v*)(idx + n_edges + e));
        const float2 a0 = pa[s.x];
        const float2 a1 = pa[s.y];
        const float2 a2 = pa[s.z];
        const float2 a3 = pa[s.w];
        const float2 q0 = pd[d.x];
        const float2 q1 = pd[d.y];
        const float2 q2 = pd[d.z];
        const float2 q3 = pd[d.w];
        float4v o0, o1;
        o0.x = a0.x + q0.x + b0;
        o0.y = a0.y + q0.y + b1;
        o0.z = a1.x + q1.x + b0;
        o0.w = a1.y + q1.y + b1;
        o1.x = a2.x + q2.x + b0;
        o1.y = a2.y + q2.y + b1;
        o1.z = a3.x + q3.x + b0;
        o1.w = a3.y + q3.y + b1;
        __builtin_nontemporal_store(o0, out + 2 * t);
        __builtin_nontemporal_store(o1, out + 2 * t + 1);
    } else {
        float* o = (float*)out;
        for (int k = e; k < n_edges; ++k) {
            const int sk = idx[k];
            const int dk = idx[n_edges + k];
            const float2 A = pa[sk];
            const float2 D = pd[dk];
            o[2 * k]     = A.x + D.x + b0;
            o[2 * k + 1] = A.y + D.y + b1;
        }
    }
}

extern "C" void kernel_launch(void* const* d_in, const int* in_sizes, int n_in,
                              void* d_out, int out_size, void* d_ws, size_t ws_size,
                              hipStream_t stream) {
    const float* x   = (const float*)d_in[0];   // [N, 128]
    const int*   idx = (const int*)d_in[1];     // [2, E] as int32
    const float* W   = (const float*)d_in[2];   // [2, 256]
    const float* b   = (const float*)d_in[3];   // [2]
    float* out = (float*)d_out;                 // [E, 2] fp32

    const int n_nodes = in_sizes[0] / IN_DIM;   // 100000
    const int n_edges = in_sizes[1] / 2;        // 625000

    float2* pa = (float2*)d_ws;                       // 800 KB
    float2* pd = (float2*)((char*)d_ws + (size_t)n_nodes * sizeof(float2));

    // Kernel 1: 64 nodes per 256-thread block (16 per wave).
    const int blocks1 = (n_nodes + 63) / 64;
    node_proj_kernel<<<blocks1, 256, 0, stream>>>(x, W, pa, pd, n_nodes);

    // Kernel 2: four edges per thread.
    const int n_quads = (n_edges + 3) / 4;
    const int blocks2 = (n_quads + 255) / 256;
    edge_score_kernel<<<blocks2, 256, 0, stream>>>(idx, pa, pd, b, (float4v*)out, n_edges);
}